// Round 2
// baseline (60.601 us; speedup 1.0000x reference)
//
#include <hip/hip_runtime.h>

#define T_LEN   8000
#define F_BANDS 128
#define CHUNK   32          // elements per thread
#define BLOCK   256         // 250 active threads cover 8000
#define EPS_F   1e-6f
#define LOG2E   1.44269504088896340736f

// raw hardware transcendentals (base-2), no libm header conflicts
__device__ __forceinline__ float hexp2(float v) { return __builtin_amdgcn_exp2f(v); }
__device__ __forceinline__ float hlog2(float v) { return __builtin_amdgcn_logf(v); }
__device__ __forceinline__ float hexp(float v)  { return hexp2(v * LOG2E); }

__global__ __launch_bounds__(BLOCK) void pcen_kernel(
    const float* __restrict__ x,
    const float* __restrict__ log_s,
    const float* __restrict__ log_alpha,
    const float* __restrict__ log_delta,
    const float* __restrict__ log_r,
    float* __restrict__ out)
{
    const int row  = blockIdx.x;            // b*F + f  (C==1)
    const int fb   = row & (F_BANDS - 1);
    const int tid  = threadIdx.x;
    const int lane = tid & 63;
    const int wv   = tid >> 6;

    // per-band scalars (uniform within block)
    const float s     = hexp(log_s[fb]);
    const float a     = 1.0f - s;
    const float alpha = hexp(log_alpha[fb]);
    const float delta = hexp(log_delta[fb]);
    const float r     = hexp(log_r[fb]);
    const float dr    = hexp2(r * hlog2(delta));       // delta^r

    const size_t base = (size_t)row * T_LEN;
    const int c0      = tid * CHUNK;
    const bool active = (c0 < T_LEN);

    // ---- load this thread's contiguous 32-element chunk into registers ----
    float4 v[CHUNK / 4];
    if (active) {
        const float4* src = reinterpret_cast<const float4*>(x + base + c0);
        #pragma unroll
        for (int m = 0; m < CHUNK / 4; ++m) v[m] = src[m];
    } else {
        #pragma unroll
        for (int m = 0; m < CHUNK / 4; ++m) v[m] = make_float4(0.f, 0.f, 0.f, 0.f);
    }
    float* xv = reinterpret_cast<float*>(v);

    // A = a^CHUNK (per-chunk decay)
    float A = a;
    #pragma unroll
    for (int i = 0; i < 5; ++i) A *= A;     // a^32

    // ---- pass 1: local scan, zero-seeded (thread 0 seeds with x[0]) ----
    // seeding f=x0 then f = a*f + s*x0 gives x0 exactly since a = 1-s.
    float fB = (tid == 0) ? xv[0] : 0.0f;
    #pragma unroll
    for (int k = 0; k < CHUNK; ++k) fB = fmaf(a, fB, s * xv[k]);

    // ---- wave-inclusive scan over chunk states with coefficient A ----
    float val = fB;
    float Ad  = A;
    #pragma unroll
    for (int d = 1; d < 64; d <<= 1) {
        float up = __shfl_up(val, d, 64);
        if (lane >= d) val = fmaf(Ad, up, val);
        Ad *= Ad;                            // A^(2d)
    }
    const float A64 = Ad;                    // A^64 (whole-wave decay)

    // ---- cross-wave combine (4 waves) ----
    __shared__ float wtot[BLOCK / 64];
    if (lane == 63) wtot[wv] = val;
    __syncthreads();
    float C = 0.0f;                          // state entering this wave
    for (int u = 0; u < wv; ++u) C = fmaf(A64, C, wtot[u]);

    // exclusive within-wave prefix
    float E = __shfl_up(val, 1, 64);
    if (lane == 0) E = 0.0f;

    // A^lane via branchless repeated squaring (exact, no log edge cases)
    float Al = 1.0f, p = A;
    #pragma unroll
    for (int b = 0; b < 6; ++b) {
        if (lane & (1 << b)) Al *= p;
        p *= p;
    }

    float carry = fmaf(Al, C, E);            // state entering this chunk
    if (tid == 0) carry = xv[0];             // recurrence then yields f0 = x[0]

    // ---- pass 2: re-scan + fused PCEN, overwrite registers, store ----
    if (active) {
        float fcur = carry;
        #pragma unroll
        for (int k = 0; k < CHUNK; ++k) {
            float xk = xv[k];
            fcur = fmaf(a, fcur, s * xk);                        // smoother
            float u = xk * hexp2(-alpha * hlog2(EPS_F + fcur));
            xv[k]   = hexp2(r * hlog2(u + delta)) - dr;
        }
        float4* dst = reinterpret_cast<float4*>(out + base + c0);
        #pragma unroll
        for (int m = 0; m < CHUNK / 4; ++m) dst[m] = v[m];
    }
}

extern "C" void kernel_launch(void* const* d_in, const int* in_sizes, int n_in,
                              void* d_out, int out_size, void* d_ws, size_t ws_size,
                              hipStream_t stream) {
    const float* x  = (const float*)d_in[0];
    const float* ls = (const float*)d_in[1];
    const float* la = (const float*)d_in[2];
    const float* ld = (const float*)d_in[3];
    const float* lr = (const float*)d_in[4];
    float* out = (float*)d_out;

    const int rows = out_size / T_LEN;       // 32*1*128 = 4096
    pcen_kernel<<<rows, BLOCK, 0, stream>>>(x, ls, la, ld, lr, out);
}

// Round 3
// 44.842 us; speedup vs baseline: 1.3514x; 1.3514x over previous
//
#include <hip/hip_runtime.h>

#define T_LEN     8000
#define NGRAN     2000          // 16B granules per row
#define NGRAN_PAD 2048
#define F_BANDS   128
#define CHUNK     16            // elements per thread
#define BLOCK     512           // 500 active threads cover 8000
#define NWAVE     (BLOCK / 64)
#define EPS_F     1e-6f
#define LOG2E     1.44269504088896340736f

// raw hardware transcendentals (base-2), no libm header conflicts
__device__ __forceinline__ float hexp2(float v) { return __builtin_amdgcn_exp2f(v); }
__device__ __forceinline__ float hlog2(float v) { return __builtin_amdgcn_logf(v); }
__device__ __forceinline__ float hexp(float v)  { return hexp2(v * LOG2E); }

// XOR involution on 16B granule index; permutes granules only WITHIN a 128B
// line (bits 0-2 xor bits 3-5), so pre-swizzled global reads stay coalesced.
__device__ __forceinline__ int swz(int g) { return g ^ ((g >> 3) & 7); }

typedef __attribute__((address_space(1))) const unsigned int gu32_t;
typedef __attribute__((address_space(3))) unsigned int lu32_t;

__global__ __launch_bounds__(BLOCK) void pcen_kernel(
    const float* __restrict__ x,
    const float* __restrict__ log_s,
    const float* __restrict__ log_alpha,
    const float* __restrict__ log_delta,
    const float* __restrict__ log_r,
    float* __restrict__ out)
{
    __shared__ float lds[NGRAN_PAD * 4];    // 32 KiB data (swizzled granules)
    __shared__ float wtot[NWAVE];

    const int row  = blockIdx.x;            // b*F + f  (C==1)
    const int fb   = row & (F_BANDS - 1);
    const int tid  = threadIdx.x;
    const int lane = tid & 63;
    const int wv   = tid >> 6;

    // per-band scalars (uniform within block)
    const float s     = hexp(log_s[fb]);
    const float a     = 1.0f - s;
    const float alpha = hexp(log_alpha[fb]);
    const float delta = hexp(log_delta[fb]);
    const float r     = hexp(log_r[fb]);
    const float dr    = hexp2(r * hlog2(delta));       // delta^r

    const float* xrow = x   + (size_t)row * T_LEN;
    float*       orow = out + (size_t)row * T_LEN;

    // ---- stage x -> LDS: linear LDS dest, pre-swizzled global source ----
    // global_load_lds writes base + lane*16 (wave-uniform base); the swizzle
    // is applied on the per-lane SOURCE address instead (within-line permute).
    #pragma unroll
    for (int c = 0; c < 4; ++c) {
        const int hbase = c * BLOCK + wv * 64;  // wave-uniform granule base
        const int h     = hbase + lane;
        int hs = swz(h);
        if (h >= NGRAN) hs = 0;                 // pad granules: load something valid
        __builtin_amdgcn_global_load_lds((gu32_t*)(xrow + 4 * hs),
                                         (lu32_t*)&lds[4 * hbase], 16, 0, 0);
    }
    __syncthreads();

    const bool active = tid < (T_LEN / CHUNK);  // tid < 500

    // ---- read this thread's 16 contiguous elements from LDS (swizzled) ----
    float4 v[CHUNK / 4];
    if (active) {
        #pragma unroll
        for (int m = 0; m < CHUNK / 4; ++m)
            v[m] = *reinterpret_cast<const float4*>(&lds[4 * swz(tid * 4 + m)]);
    } else {
        #pragma unroll
        for (int m = 0; m < CHUNK / 4; ++m)
            v[m] = make_float4(0.f, 0.f, 0.f, 0.f);
    }
    float* xv = reinterpret_cast<float*>(v);

    // A = a^CHUNK (per-chunk decay)
    float A = a;
    #pragma unroll
    for (int i = 0; i < 4; ++i) A *= A;     // a^16

    // ---- pass 1: local scan, zero-seeded (thread 0 seeds with x[0]) ----
    float fB = (tid == 0) ? xv[0] : 0.0f;
    #pragma unroll
    for (int k = 0; k < CHUNK; ++k) fB = fmaf(a, fB, s * xv[k]);

    // ---- wave-inclusive scan over chunk states with coefficient A ----
    float val = fB;
    float Ad  = A;
    #pragma unroll
    for (int d = 1; d < 64; d <<= 1) {
        float up = __shfl_up(val, d, 64);
        if (lane >= d) val = fmaf(Ad, up, val);
        Ad *= Ad;                            // A^(2d)
    }
    const float Aw = Ad;                     // A^64 = a^(64*CHUNK), per-wave decay

    // ---- cross-wave combine ----
    if (lane == 63) wtot[wv] = val;
    __syncthreads();
    float C = 0.0f;                          // state entering this wave
    for (int u = 0; u < wv; ++u) C = fmaf(Aw, C, wtot[u]);

    // exclusive within-wave prefix
    float E = __shfl_up(val, 1, 64);
    if (lane == 0) E = 0.0f;

    // A^lane via branchless repeated squaring
    float Al = 1.0f, p = A;
    #pragma unroll
    for (int b = 0; b < 6; ++b) {
        if (lane & (1 << b)) Al *= p;
        p *= p;
    }

    float carry = fmaf(Al, C, E);            // state entering this chunk
    if (tid == 0) carry = xv[0];             // recurrence then yields f0 = x[0]

    // ---- pass 2: re-scan + fused PCEN, write results back to LDS ----
    if (active) {
        float fcur = carry;
        #pragma unroll
        for (int k = 0; k < CHUNK; ++k) {
            float xk = xv[k];
            fcur = fmaf(a, fcur, s * xk);                        // smoother
            float u = xk * hexp2(-alpha * hlog2(EPS_F + fcur));
            xv[k]   = hexp2(r * hlog2(u + delta)) - dr;
        }
        #pragma unroll
        for (int m = 0; m < CHUNK / 4; ++m)
            *reinterpret_cast<float4*>(&lds[4 * swz(tid * 4 + m)]) = v[m];
    }
    __syncthreads();

    // ---- coalesced store sweep from LDS ----
    #pragma unroll
    for (int c = 0; c < 4; ++c) {
        const int h = c * BLOCK + tid;
        if (h < NGRAN) {
            float4 val4 = *reinterpret_cast<const float4*>(&lds[4 * swz(h)]);
            *reinterpret_cast<float4*>(&orow[4 * h]) = val4;
        }
    }
}

extern "C" void kernel_launch(void* const* d_in, const int* in_sizes, int n_in,
                              void* d_out, int out_size, void* d_ws, size_t ws_size,
                              hipStream_t stream) {
    const float* x  = (const float*)d_in[0];
    const float* ls = (const float*)d_in[1];
    const float* la = (const float*)d_in[2];
    const float* ld = (const float*)d_in[3];
    const float* lr = (const float*)d_in[4];
    float* out = (float*)d_out;

    const int rows = out_size / T_LEN;       // 32*1*128 = 4096
    pcen_kernel<<<rows, BLOCK, 0, stream>>>(x, ls, la, ld, lr, out);
}

// Round 5
// 44.794 us; speedup vs baseline: 1.3529x; 1.0011x over previous
//
#include <hip/hip_runtime.h>

#define T_LEN     8000
#define NGRAN     2000          // 16B granules per row
#define NGRAN_PAD 2048
#define F_BANDS   128
#define CHUNK     16            // elements per thread
#define BLOCK     512           // 500 active threads cover 8000
#define NWAVE     (BLOCK / 64)
#define GPW       256           // granules per wave (64 lanes * 4 granules)
#define EPS_F     1e-6f
#define LOG2E     1.44269504088896340736f

typedef float  floatx4 __attribute__((ext_vector_type(4)));

// raw hardware transcendentals (base-2), no libm header conflicts
__device__ __forceinline__ float hexp2(float v) { return __builtin_amdgcn_exp2f(v); }
__device__ __forceinline__ float hlog2(float v) { return __builtin_amdgcn_logf(v); }
__device__ __forceinline__ float hexp(float v)  { return hexp2(v * LOG2E); }

// XOR involution on 16B granule index; permutes granules only WITHIN a 128B
// line (bits 0-2 xor bits 3-5), so pre-swizzled global reads stay coalesced.
__device__ __forceinline__ int swz(int g) { return g ^ ((g >> 3) & 7); }

typedef __attribute__((address_space(1))) const unsigned int gu32_t;
typedef __attribute__((address_space(3))) unsigned int lu32_t;

__global__ __launch_bounds__(BLOCK) void pcen_kernel(
    const float* __restrict__ x,
    const float* __restrict__ log_s,
    const float* __restrict__ log_alpha,
    const float* __restrict__ log_delta,
    const float* __restrict__ log_r,
    float* __restrict__ out)
{
    __shared__ float lds[NGRAN_PAD * 4];    // 32 KiB data (swizzled granules)
    __shared__ float wtot[NWAVE];

    const int row  = blockIdx.x;            // b*F + f  (C==1)
    const int fb   = row & (F_BANDS - 1);
    const int tid  = threadIdx.x;
    const int lane = tid & 63;
    const int wv   = tid >> 6;

    const float* xrow = x   + (size_t)row * T_LEN;
    float*       orow = out + (size_t)row * T_LEN;

    // ---- wave-local staging: each wave stages ITS OWN granule range ----
    // linear LDS dest (wave-uniform base + lane*16), pre-swizzled source.
    #pragma unroll
    for (int c = 0; c < 4; ++c) {
        const int hbase = wv * GPW + c * 64;    // wave-uniform granule base
        const int h     = hbase + lane;
        int hs = swz(h);
        if (h >= NGRAN) hs = 0;                 // pad granules: any valid addr
        __builtin_amdgcn_global_load_lds((gu32_t*)(xrow + 4 * hs),
                                         (lu32_t*)&lds[4 * hbase], 16, 0, 0);
    }

    // per-band scalars (uniform within block) — overlaps with load latency
    const float s     = hexp(log_s[fb]);
    const float a     = 1.0f - s;
    const float alpha = hexp(log_alpha[fb]);
    const float delta = hexp(log_delta[fb]);
    const float r     = hexp(log_r[fb]);
    const float dr    = hexp2(r * hlog2(delta));       // delta^r

    // wait for THIS wave's staging loads only (no block barrier)
    asm volatile("s_waitcnt vmcnt(0)" ::: "memory");
    __builtin_amdgcn_sched_barrier(0);

    const bool active = tid < (T_LEN / CHUNK);  // tid < 500

    // ---- read this thread's 16 contiguous elements from LDS (swizzled) ----
    floatx4 v[CHUNK / 4];
    if (active) {
        #pragma unroll
        for (int m = 0; m < CHUNK / 4; ++m)
            v[m] = *reinterpret_cast<const floatx4*>(&lds[4 * swz(tid * 4 + m)]);
    } else {
        #pragma unroll
        for (int m = 0; m < CHUNK / 4; ++m)
            v[m] = (floatx4)(0.0f);
    }
    float* xv = reinterpret_cast<float*>(v);

    // A = a^CHUNK (per-chunk decay)
    float A = a;
    #pragma unroll
    for (int i = 0; i < 4; ++i) A *= A;     // a^16

    // ---- pass 1: local scan, zero-seeded (thread 0 seeds with x[0]) ----
    float fB = (tid == 0) ? xv[0] : 0.0f;
    #pragma unroll
    for (int k = 0; k < CHUNK; ++k) fB = fmaf(a, fB, s * xv[k]);

    // ---- wave-inclusive scan over chunk states with coefficient A ----
    float val = fB;
    float Ad  = A;
    #pragma unroll
    for (int d = 1; d < 64; d <<= 1) {
        float up = __shfl_up(val, d, 64);
        if (lane >= d) val = fmaf(Ad, up, val);
        Ad *= Ad;                            // A^(2d)
    }
    const float Aw = Ad;                     // A^64, per-wave decay

    // ---- cross-wave combine: the ONLY block-wide barrier ----
    if (lane == 63) wtot[wv] = val;
    __syncthreads();
    float C = 0.0f;                          // state entering this wave
    for (int u = 0; u < wv; ++u) C = fmaf(Aw, C, wtot[u]);

    // exclusive within-wave prefix
    float E = __shfl_up(val, 1, 64);
    if (lane == 0) E = 0.0f;

    // A^lane via branchless repeated squaring
    float Al = 1.0f, p = A;
    #pragma unroll
    for (int b = 0; b < 6; ++b) {
        if (lane & (1 << b)) Al *= p;
        p *= p;
    }

    float carry = fmaf(Al, C, E);            // state entering this chunk
    if (tid == 0) carry = xv[0];             // recurrence then yields f0 = x[0]

    // ---- pass 2: re-scan + fused PCEN, results back to LDS (wave-local) ----
    if (active) {
        float fcur = carry;
        #pragma unroll
        for (int k = 0; k < CHUNK; ++k) {
            float xk = xv[k];
            fcur = fmaf(a, fcur, s * xk);                        // smoother
            float u = xk * hexp2(-alpha * hlog2(EPS_F + fcur));
            xv[k]   = hexp2(r * hlog2(u + delta)) - dr;
        }
        #pragma unroll
        for (int m = 0; m < CHUNK / 4; ++m)
            *reinterpret_cast<floatx4*>(&lds[4 * swz(tid * 4 + m)]) = v[m];
    }
    // no barrier: store sweep below reads only THIS wave's granule range,
    // written by this wave's own threads (lgkmcnt dependency, compiler-tracked)

    // ---- wave-local coalesced store sweep (non-temporal: don't evict L3) ----
    #pragma unroll
    for (int c = 0; c < 4; ++c) {
        const int h = wv * GPW + c * 64 + lane;
        if (h < NGRAN) {
            floatx4 val4 = *reinterpret_cast<const floatx4*>(&lds[4 * swz(h)]);
            __builtin_nontemporal_store(val4, reinterpret_cast<floatx4*>(&orow[4 * h]));
        }
    }
}

extern "C" void kernel_launch(void* const* d_in, const int* in_sizes, int n_in,
                              void* d_out, int out_size, void* d_ws, size_t ws_size,
                              hipStream_t stream) {
    const float* x  = (const float*)d_in[0];
    const float* ls = (const float*)d_in[1];
    const float* la = (const float*)d_in[2];
    const float* ld = (const float*)d_in[3];
    const float* lr = (const float*)d_in[4];
    float* out = (float*)d_out;

    const int rows = out_size / T_LEN;       // 32*1*128 = 4096
    pcen_kernel<<<rows, BLOCK, 0, stream>>>(x, ls, la, ld, lr, out);
}